// Round 5
// baseline (324.484 us; speedup 1.0000x reference)
//
#include <hip/hip_runtime.h>
#include <hip/hip_bf16.h>
#include <cstdint>

// ---------------------------------------------------------------------------
// InteractionMHA, fp32 I/O, bf16-MFMA compute.
// Per branch:
//   Q  = rep_q  @ Wq^T + bq           (gemm_kernel -> BQ bf16, NT stores)
//   K  = rep_kv @ Wk^T + bk           (gemm_kernel -> BK bf16, NT stores)
//   Vt = Wv @ rep_kv^T (+bv per row)  (gemm_kernel -> BV bf16 transposed, NT)
//   X  = softmax(Q K^T/16) V          (attn_kernel, X -> BQ in-place, NT)
//   out = gelu(X @ Wm^T + bm)         (gemm_out, 2-phase prefetch, fp32 NT out)
//
// NT stores on all producer->consumer ws traffic: MI355X per-XCD L2s are not
// cross-coherent; consumer reads of dirty REMOTE-L2 lines serialize at fabric
// latency (round-4 evidence: gemm_out 60us vs twin gemm_kernel 11us, FETCH
// 11MB for a 21MB read, MfmaUtil 3%). NT pushes lines to the shared level.
// ---------------------------------------------------------------------------

typedef short s16x8 __attribute__((ext_vector_type(8)));
typedef float f32x4 __attribute__((ext_vector_type(4)));

__device__ __forceinline__ void nt_store_bf16(__bf16* p, float v) {
  __bf16 b = (__bf16)v;
  __builtin_nontemporal_store(__builtin_bit_cast(short, b), (short*)p);
}
__device__ __forceinline__ float fast_gelu(float x) {
  // exact gelu via A&S 7.1.26 erf (|eps| <= 1.5e-7)
  float ax = fabsf(x);
  float t = 1.0f / (1.0f + 0.3275911f * (ax * 0.70710678f));
  float y = t * (0.254829592f + t * (-0.284496736f + t * (1.421413741f +
            t * (-1.453152027f + t * 1.061405429f))));
  float er = 1.0f - y * __expf(-0.5f * ax * ax);
  er = (x < 0.f) ? -er : er;
  return 0.5f * x * (1.0f + er);
}

__global__ void sentinel_kernel(float* out, float v) {
  if (threadIdx.x == 0 && blockIdx.x == 0) out[0] = v;
}

__global__ void scan_kernel(const int* __restrict__ na, int* __restrict__ offs,
                            int B, int total, float* out) {
  if (threadIdx.x != 0 || blockIdx.x != 0) return;
  long long s = 0;
  for (int b = 0; b < B; ++b) s += na[b];
  if (s == (long long)total) {
    int acc = 0;
    for (int b = 0; b < B; ++b) { offs[b] = acc; acc += na[b]; }
    offs[B] = acc;
    return;
  }
  const long long* na64 = (const long long*)na;
  s = 0;
  for (int b = 0; b < B; ++b) s += na64[b];
  if (s == (long long)total) {
    int acc = 0;
    for (int b = 0; b < B; ++b) { offs[b] = acc; acc += (int)na64[b]; }
    offs[B] = acc;
    return;
  }
  for (int b = 0; b <= B; ++b) offs[b] = 0;
  out[0] = 31337.0f;
}

// ---------- GEMM: C[M][N] = A[M][256] @ Bw[N][256]^T + bias (fp32->bf16) ---
__global__ __launch_bounds__(256) void gemm_kernel(
    const float* __restrict__ A, const float* __restrict__ Bw,
    const float* __restrict__ bias, __bf16* __restrict__ C,
    int N, int biasRow)
{
  __shared__ __bf16 At[128 * 32];
  __shared__ __bf16 Bt[128 * 32];
  const int t = threadIdx.x;
  const int lane = t & 63, w = t >> 6;
  const int wr = w >> 1, wc = w & 1;
  const int l15 = lane & 15, l4 = lane >> 4;
  const int by = blockIdx.x, bx = blockIdx.y;

  f32x4 acc[4][4];
  for (int m = 0; m < 4; ++m)
    for (int nn = 0; nn < 4; ++nn) acc[m][nn] = (f32x4){0.f, 0.f, 0.f, 0.f};

  for (int kk = 0; kk < 256; kk += 32) {
    for (int j = 0; j < 2; ++j) {
      int c = t + j * 256;
      int row = c >> 2, off0 = (c & 3) * 8;
      const float* ap = A + (size_t)(by * 128 + row) * 256 + kk + off0;
      const float* bp = Bw + (size_t)(bx * 128 + row) * 256 + kk + off0;
      float4 a0 = *(const float4*)ap, a1 = *(const float4*)(ap + 4);
      float4 b0 = *(const float4*)bp, b1 = *(const float4*)(bp + 4);
      union { s16x8 v; __bf16 e[8]; } pa, pb;
      pa.e[0] = (__bf16)a0.x; pa.e[1] = (__bf16)a0.y; pa.e[2] = (__bf16)a0.z; pa.e[3] = (__bf16)a0.w;
      pa.e[4] = (__bf16)a1.x; pa.e[5] = (__bf16)a1.y; pa.e[6] = (__bf16)a1.z; pa.e[7] = (__bf16)a1.w;
      pb.e[0] = (__bf16)b0.x; pb.e[1] = (__bf16)b0.y; pb.e[2] = (__bf16)b0.z; pb.e[3] = (__bf16)b0.w;
      pb.e[4] = (__bf16)b1.x; pb.e[5] = (__bf16)b1.y; pb.e[6] = (__bf16)b1.z; pb.e[7] = (__bf16)b1.w;
      *(s16x8*)(&At[row * 32 + off0]) = pa.v;
      *(s16x8*)(&Bt[row * 32 + off0]) = pb.v;
    }
    __syncthreads();
    s16x8 af[4], bfr[4];
    for (int m = 0; m < 4; ++m)
      af[m] = *(const s16x8*)(&At[(wr * 64 + m * 16 + l15) * 32 + l4 * 8]);
    for (int nn = 0; nn < 4; ++nn)
      bfr[nn] = *(const s16x8*)(&Bt[(wc * 64 + nn * 16 + l15) * 32 + l4 * 8]);
    for (int m = 0; m < 4; ++m)
      for (int nn = 0; nn < 4; ++nn)
        acc[m][nn] = __builtin_amdgcn_mfma_f32_16x16x32_bf16(af[m], bfr[nn], acc[m][nn], 0, 0, 0);
    __syncthreads();
  }

  for (int m = 0; m < 4; ++m) {
    int row0 = by * 128 + wr * 64 + m * 16 + l4 * 4;
    for (int nn = 0; nn < 4; ++nn) {
      int col = bx * 128 + wc * 64 + nn * 16 + l15;
      float bc = biasRow ? 0.f : bias[col];
      for (int r = 0; r < 4; ++r) {
        int row = row0 + r;
        float v = acc[m][nn][r] + (biasRow ? bias[row] : bc);
        nt_store_bf16(&C[(size_t)row * N + col], v);
      }
    }
  }
}

// ---------- out-proj: out = gelu(X[M][256] @ Wm[256][256]^T + bm), fp32 ----
// 2-phase reg-prefetch: tile kk+1 global loads issued before tile kk's MFMAs.
__global__ __launch_bounds__(256) void gemm_out(
    const __bf16* __restrict__ A, const float* __restrict__ Bw,
    const float* __restrict__ bias, float* __restrict__ C, int N)
{
  __shared__ __bf16 At[128 * 32];
  __shared__ __bf16 Bt[128 * 32];
  const int t = threadIdx.x;
  const int lane = t & 63, w = t >> 6;
  const int wr = w >> 1, wc = w & 1;
  const int l15 = lane & 15, l4 = lane >> 4;
  const int by = blockIdx.x, bx = blockIdx.y;

  // per-thread staging coords (two 16B chunks per tile per matrix)
  const int c0 = t, c1 = t + 256;
  const int r0 = c0 >> 2, o0 = (c0 & 3) * 8;
  const int r1 = c1 >> 2, o1 = (c1 & 3) * 8;
  const __bf16* a0p = A + (size_t)(by * 128 + r0) * 256 + o0;
  const __bf16* a1p = A + (size_t)(by * 128 + r1) * 256 + o1;
  const float*  b0p = Bw + (size_t)(bx * 128 + r0) * 256 + o0;
  const float*  b1p = Bw + (size_t)(bx * 128 + r1) * 256 + o1;

  f32x4 acc[4][4];
  for (int m = 0; m < 4; ++m)
    for (int nn = 0; nn < 4; ++nn) acc[m][nn] = (f32x4){0.f, 0.f, 0.f, 0.f};

  s16x8 sa0, sa1;
  float4 sb00, sb01, sb10, sb11;
  // prologue: tile 0
  sa0 = *(const s16x8*)(a0p); sa1 = *(const s16x8*)(a1p);
  sb00 = *(const float4*)(b0p); sb01 = *(const float4*)(b0p + 4);
  sb10 = *(const float4*)(b1p); sb11 = *(const float4*)(b1p + 4);

  for (int it = 0; it < 8; ++it) {
    if (it) __syncthreads();                 // prev tile's readers done
    {
      union { s16x8 v; __bf16 e[8]; } pb;
      pb.e[0] = (__bf16)sb00.x; pb.e[1] = (__bf16)sb00.y; pb.e[2] = (__bf16)sb00.z; pb.e[3] = (__bf16)sb00.w;
      pb.e[4] = (__bf16)sb01.x; pb.e[5] = (__bf16)sb01.y; pb.e[6] = (__bf16)sb01.z; pb.e[7] = (__bf16)sb01.w;
      *(s16x8*)(&At[r0 * 32 + o0]) = sa0;
      *(s16x8*)(&Bt[r0 * 32 + o0]) = pb.v;
      pb.e[0] = (__bf16)sb10.x; pb.e[1] = (__bf16)sb10.y; pb.e[2] = (__bf16)sb10.z; pb.e[3] = (__bf16)sb10.w;
      pb.e[4] = (__bf16)sb11.x; pb.e[5] = (__bf16)sb11.y; pb.e[6] = (__bf16)sb11.z; pb.e[7] = (__bf16)sb11.w;
      *(s16x8*)(&At[r1 * 32 + o1]) = sa1;
      *(s16x8*)(&Bt[r1 * 32 + o1]) = pb.v;
    }
    __syncthreads();                         // tile ready
    if (it < 7) {                            // prefetch next (retires under MFMA)
      int kk = (it + 1) * 32;
      sa0 = *(const s16x8*)(a0p + kk); sa1 = *(const s16x8*)(a1p + kk);
      sb00 = *(const float4*)(b0p + kk); sb01 = *(const float4*)(b0p + kk + 4);
      sb10 = *(const float4*)(b1p + kk); sb11 = *(const float4*)(b1p + kk + 4);
    }
    s16x8 af[4], bfr[4];
    for (int m = 0; m < 4; ++m)
      af[m] = *(const s16x8*)(&At[(wr * 64 + m * 16 + l15) * 32 + l4 * 8]);
    for (int nn = 0; nn < 4; ++nn)
      bfr[nn] = *(const s16x8*)(&Bt[(wc * 64 + nn * 16 + l15) * 32 + l4 * 8]);
    for (int m = 0; m < 4; ++m)
      for (int nn = 0; nn < 4; ++nn)
        acc[m][nn] = __builtin_amdgcn_mfma_f32_16x16x32_bf16(af[m], bfr[nn], acc[m][nn], 0, 0, 0);
  }

  for (int m = 0; m < 4; ++m) {
    int row0 = by * 128 + wr * 64 + m * 16 + l4 * 4;
    for (int nn = 0; nn < 4; ++nn) {
      int col = bx * 128 + wc * 64 + nn * 16 + l15;
      float bc = bias[col];
      for (int r = 0; r < 4; ++r) {
        int row = row0 + r;
        float v = fast_gelu(acc[m][nn][r] + bc);
        __builtin_nontemporal_store(v, &C[(size_t)row * N + col]);
      }
    }
  }
}

// ---------- attention: X = softmax(Q K^T / 16, key-masked) V --------------
// 1 block/graph, 8 waves. Klds staged once; Plds reuses the same LDS after a
// barrier. Wave w: QK^T+softmax for q rows [w*16,+16); PV for d cols
// [w*32,+32) over ALL q rows (V read once). V frags prefetched under softmax.
#define KSTR 264
#define PSTR 136
__global__ __launch_bounds__(512, 2) void attn_kernel(
    const __bf16* __restrict__ Q, const __bf16* __restrict__ Km,
    const __bf16* __restrict__ Vt, __bf16* __restrict__ X,
    const int* __restrict__ offs, int total)
{
  __shared__ __bf16 smem[128 * KSTR];                 // 67.6 KB, K then P
  __bf16 (*Klds)[KSTR] = (__bf16(*)[KSTR])smem;
  __bf16 (*Plds)[PSTR] = (__bf16(*)[PSTR])smem;

  const int g = blockIdx.x;
  const int off = offs[g];
  const int n = offs[g + 1] - off;
  const int t = threadIdx.x, lane = t & 63, w = t >> 6;
  const int l15 = lane & 15, l4 = lane >> 4;
  const bool qact = (w * 16) < n;

  // ---- stage K rows 0..127 (overrun beyond n reads valid ws, masked later)
  uint4 kst[8];
  #pragma unroll
  for (int j = 0; j < 8; ++j) {
    int row = j * 16 + (t >> 5);
    kst[j] = *(const uint4*)((const char*)(Km + (size_t)(off + row) * 256) + (t & 31) * 16);
  }
  // ---- Q frags for this wave's 16 rows
  s16x8 qf[8];
  if (qact) {
    int qr = w * 16 + l15; if (qr >= n) qr = n - 1;
    const __bf16* qp = Q + (size_t)(off + qr) * 256 + l4 * 8;
    #pragma unroll
    for (int kk = 0; kk < 8; ++kk) qf[kk] = *(const s16x8*)(qp + kk * 32);
  }
  #pragma unroll
  for (int j = 0; j < 8; ++j) {
    int row = j * 16 + (t >> 5);
    *(uint4*)((char*)&Klds[row][0] + (t & 31) * 16) = kst[j];
  }
  __syncthreads();

  // ---- S = Q K^T (from Klds)
  f32x4 sacc[8];
  #pragma unroll
  for (int i = 0; i < 8; ++i) sacc[i] = (f32x4){0.f, 0.f, 0.f, 0.f};
  if (qact) {
    #pragma unroll
    for (int kt = 0; kt < 8; ++kt) {
      if (kt * 16 < n) {
        const __bf16* kp = &Klds[kt * 16 + l15][l4 * 8];
        #pragma unroll
        for (int kk = 0; kk < 8; ++kk) {
          s16x8 kf = *(const s16x8*)(kp + kk * 32);
          sacc[kt] = __builtin_amdgcn_mfma_f32_16x16x32_bf16(qf[kk], kf, sacc[kt], 0, 0, 0);
        }
      }
    }
  }

  // ---- V prefetch (retires under softmax + barriers); d = w*32+dt*16+l15
  const int dbase = w * 32;
  s16x8 vf0[4], vf1[4];
  {
    int d0 = dbase + l15, d1 = dbase + 16 + l15;
    #pragma unroll
    for (int ks = 0; ks < 4; ++ks) {
      int kc = off + ks * 32 + l4 * 8;
      if (kc > total - 8) kc = total - 8;             // P=0 there; stays finite
      vf0[ks] = *(const s16x8*)(Vt + (size_t)d0 * total + kc);
      vf1[ks] = *(const s16x8*)(Vt + (size_t)d1 * total + kc);
    }
  }
  __syncthreads();                                    // Klds reads complete

  // ---- softmax (registers) -> Plds (bf16)
  if (qact) {
    #pragma unroll
    for (int r = 0; r < 4; ++r) {
      float sv[8];
      float m = -1e30f;
      #pragma unroll
      for (int kt = 0; kt < 8; ++kt) {
        int key = kt * 16 + l15;
        float v = (key < n) ? sacc[kt][r] * 0.0625f : -1e30f;
        sv[kt] = v; m = fmaxf(m, v);
      }
      for (int o = 1; o < 16; o <<= 1) m = fmaxf(m, __shfl_xor(m, o));
      float p[8], sum = 0.f;
      #pragma unroll
      for (int kt = 0; kt < 8; ++kt) { p[kt] = __expf(sv[kt] - m); sum += p[kt]; }
      for (int o = 1; o < 16; o <<= 1) sum += __shfl_xor(sum, o);
      float inv = 1.f / sum;
      int q = w * 16 + l4 * 4 + r;
      #pragma unroll
      for (int kt = 0; kt < 8; ++kt)
        Plds[q][kt * 16 + l15] = (__bf16)(p[kt] * inv);   // masked keys -> 0
    }
  }
  __syncthreads();                                    // Plds complete

  // ---- PV: wave w computes X[all 128 q][d in w*32..w*32+32)
  f32x4 xacc[2][8];
  #pragma unroll
  for (int dt = 0; dt < 2; ++dt)
    #pragma unroll
    for (int qm = 0; qm < 8; ++qm) xacc[dt][qm] = (f32x4){0.f, 0.f, 0.f, 0.f};

  #pragma unroll
  for (int qm = 0; qm < 8; ++qm) {
    #pragma unroll
    for (int ks = 0; ks < 4; ++ks) {
      if (ks * 32 < n) {
        s16x8 pa = *(const s16x8*)(&Plds[qm * 16 + l15][ks * 32 + l4 * 8]);
        xacc[0][qm] = __builtin_amdgcn_mfma_f32_16x16x32_bf16(pa, vf0[ks], xacc[0][qm], 0, 0, 0);
        xacc[1][qm] = __builtin_amdgcn_mfma_f32_16x16x32_bf16(pa, vf1[ks], xacc[1][qm], 0, 0, 0);
      }
    }
  }

  // ---- store X (bf16, NT) rows q<n
  #pragma unroll
  for (int dt = 0; dt < 2; ++dt)
    #pragma unroll
    for (int qm = 0; qm < 8; ++qm)
      #pragma unroll
      for (int r = 0; r < 4; ++r) {
        int q = qm * 16 + l4 * 4 + r;
        if (q < n)
          nt_store_bf16(&X[(size_t)(off + q) * 256 + dbase + dt * 16 + l15],
                        xacc[dt][qm][r]);
      }
}

// ---------------------------------------------------------------------------
extern "C" void kernel_launch(void* const* d_in, const int* in_sizes, int n_in,
                              void* d_out, int out_size, void* d_ws, size_t ws_size,
                              hipStream_t stream) {
  const float* rep2d = (const float*)d_in[0];
  const float* rep3d = (const float*)d_in[1];
  const int*   na    = (const int*)d_in[2];
  const float* wq23 = (const float*)d_in[3];  const float* bq23 = (const float*)d_in[4];
  const float* wk23 = (const float*)d_in[5];  const float* bk23 = (const float*)d_in[6];
  const float* wv23 = (const float*)d_in[7];  const float* bv23 = (const float*)d_in[8];
  const float* wq32 = (const float*)d_in[9];  const float* bq32 = (const float*)d_in[10];
  const float* wk32 = (const float*)d_in[11]; const float* bk32 = (const float*)d_in[12];
  const float* wv32 = (const float*)d_in[13]; const float* bv32 = (const float*)d_in[14];
  const float* wm23 = (const float*)d_in[15]; const float* bm23 = (const float*)d_in[16];
  const float* wm32 = (const float*)d_in[17]; const float* bm32 = (const float*)d_in[18];

  const int B = in_sizes[2];
  const int total = in_sizes[0] / 256;           // 40960
  float* out = (float*)d_out;

  char* ws = (char*)d_ws;
  const size_t SZ = (size_t)total * 256 * sizeof(__bf16);  // 20.97 MB
  const size_t need = 8192 + 3 * SZ;                       // 62.9 MB (proven ok)
  if (ws_size < need) {
    sentinel_kernel<<<1, 64, 0, stream>>>(out, 54321.0f);
    return;
  }
  int*    offs = (int*)ws;
  __bf16* BQ = (__bf16*)(ws + 8192);             // Q, then X in-place
  __bf16* BK = (__bf16*)(ws + 8192 + SZ);
  __bf16* BV = (__bf16*)(ws + 8192 + 2 * SZ);    // transposed V [256][total]

  scan_kernel<<<1, 64, 0, stream>>>(na, offs, B, total, out);

  dim3 blk(256);
  dim3 gP(total / 128, 2);   // [total,256] gemms
  dim3 gV(2, total / 128);   // transposed-V gemm: M=256, N=total
  dim3 gA(B);                // attention: 1 block/graph
  dim3 blkA(512);

  // branch 2d -> 3d
  gemm_kernel<<<gP, blk, 0, stream>>>(rep2d, wq23, bq23, BQ, 256, 0);
  gemm_kernel<<<gP, blk, 0, stream>>>(rep3d, wk23, bk23, BK, 256, 0);
  gemm_kernel<<<gV, blk, 0, stream>>>(wv23, rep3d, bv23, BV, total, 1);
  attn_kernel<<<gA, blkA, 0, stream>>>(BQ, BK, BV, BQ, offs, total);
  gemm_out<<<gP, blk, 0, stream>>>(BQ, wm23, bm23, out, 256);

  // branch 3d -> 2d
  gemm_kernel<<<gP, blk, 0, stream>>>(rep3d, wq32, bq32, BQ, 256, 0);
  gemm_kernel<<<gP, blk, 0, stream>>>(rep2d, wk32, bk32, BK, 256, 0);
  gemm_kernel<<<gV, blk, 0, stream>>>(wv32, rep2d, bv32, BV, total, 1);
  attn_kernel<<<gA, blkA, 0, stream>>>(BQ, BK, BV, BQ, offs, total);
  gemm_out<<<gP, blk, 0, stream>>>(BQ, wm32, bm32, out + (size_t)total * 256, 256);
}